// Round 1
// 158.222 us; speedup vs baseline: 1.0044x; 1.0044x over previous
//
#include <hip/hip_runtime.h>

#define AFROMZERO 0.02f
#define AFROMC    0.01f
#define OSF       15.0f
#define LOG2E     1.4426950408889634f
#define EXPMAX2   (50.0f * LOG2E)   // reference clips f_exp at +/-50 in natural-log units

// zmax_calc with c = 1.0 (as used by likelihood()).
__device__ __forceinline__ float zmax_calc(float a, float b) {
    if (a < AFROMZERO) return fminf(b, 1.0f);          // c=1: (c>b)? b/c : 1
    if (fabsf(a - 1.0f) < AFROMC) return b / (b + 1.0f);
    float d  = (b - 1.0f) * (b - 1.0f) + 4.0f * a * b;
    float zg = 0.5f * (b + 1.0f - sqrtf(d)) / (1.0f - a);
    if (zg > 0.9999f && b > 100.0f) zg = fminf(zg, 1.0f - a / b);
    return zg;
}

// Base-2 per-(param,m) constants:
//   f2(z) = C2 - be2*(1/z) - log2(z) + a*log2(1-z)  ==  f_exp * log2(e)
__device__ __forceinline__ void set_consts2(float a, float b, float mTv,
                                            float& C2, float& be2) {
    float be = b * mTv * mTv;
    float zm = zmax_calc(a, be);
    be2 = be * LOG2E;
    float c = be2 / zm + log2f(zm);
    if (a >= AFROMZERO) c -= a * log2f(1.0f - zm);
    C2 = c;
}

__global__ __launch_bounds__(256) void lund_weight_kernel(
    const float* __restrict__ z,      // (B, 128, 25)
    const float* __restrict__ mT,     // (B, 128)
    const int*   __restrict__ obs,    // (B, 2) -> mult = obs[2b]
    const float* __restrict__ pa_p,
    const float* __restrict__ pb_p,
    const float* __restrict__ base_p, // (2,)
    float* __restrict__ out)          // (B,)
{
    __shared__ float s_part[4];

    const int tid  = threadIdx.x;
    const int r0   = blockIdx.x * 2;
    const int half = tid >> 7;        // 0 -> row r0, 1 -> row r0+1
    const int m    = tid & 127;
    const int row  = r0 + half;
    const int mult = obs[2 * row];
    const bool live = m < mult;

    // ---- per-thread record load: 25 consecutive floats (100 B), issued early.
    // A wave's 64 records form one contiguous 6.4 KB span -> L1/L2 absorb the
    // 100 B-stride overlap; HBM traffic identical to the old DMA staging.
    // Whole-dead waves (m-range >= mult) skip under execz -> prefix-only reads.
    float v[25];
    {
        const float* gp = z + (size_t)row * 3200 + m * 25;
        if (live) {
            #pragma unroll
            for (int c = 0; c < 6; ++c)
                __builtin_memcpy(&v[4 * c], gp + 4 * c, 16);  // align-4 dwordx4
            v[24] = gp[24];
        }
    }

    // ---- per-thread (param,m) constants; trans chain hides the loads in flight
    const float pa = pa_p[0], pb = pb_p[0];
    const float a0 = base_p[0], b0 = base_p[1];
    const float an = (pa < AFROMZERO) ? 0.0f : pa;
    const float ao = (a0 < AFROMZERO) ? 0.0f : a0;

    const float mTv = mT[(size_t)row * 128 + m];
    float Cn2, ben2, Co2, beo2;
    set_consts2(pa, pb, mTv, Cn2, ben2);
    set_consts2(a0, b0, mTv, Co2, beo2);

    float w = 1.0f;
    if (live) {
        float facN = 1.0f, facD = 1.0f;
        #pragma unroll
        for (int k = 0; k < 25; ++k) {
            float zz  = v[k];
            bool  act = (zz != 0.0f);
            float zs  = act ? zz : 0.5f;
            float rz  = __builtin_amdgcn_rcpf(zs);
            float lz  = __builtin_amdgcn_logf(zs);          // log2
            float l1  = __builtin_amdgcn_logf(1.0f - zs);   // log2
            float fn  = fmaf(-ben2, rz, Cn2) + fmaf(an, l1, -lz);
            float fo  = fmaf(-beo2, rz, Co2) + fmaf(ao, l1, -lz);
            fn = fminf(fmaxf(fn, -EXPMAX2), EXPMAX2);
            fo = fminf(fmaxf(fo, -EXPMAX2), EXPMAX2);
            float Ln = __builtin_amdgcn_exp2f(fn);
            float Lo = __builtin_amdgcn_exp2f(fo);
            float fN = (k == 0) ? Ln : (OSF - Ln);
            float fD = (k == 0) ? Lo : (OSF - Lo);
            facN *= act ? fN : 1.0f;
            facD *= act ? fD : 1.0f;
        }
        w = facN / facD;
    }

    // 64-lane product reduction (waves 0/1 -> row r0, waves 2/3 -> row r0+1)
    for (int mask = 1; mask < 64; mask <<= 1)
        w *= __shfl_xor(w, mask, 64);
    if ((tid & 63) == 0) s_part[tid >> 6] = w;
    __syncthreads();
    if (tid == 0)   out[r0]     = s_part[0] * s_part[1];
    if (tid == 128) out[r0 + 1] = s_part[2] * s_part[3];
}

extern "C" void kernel_launch(void* const* d_in, const int* in_sizes, int n_in,
                              void* d_out, int out_size, void* d_ws, size_t ws_size,
                              hipStream_t stream) {
    const float* z    = (const float*)d_in[0];
    const float* mT   = (const float*)d_in[1];
    const int*   obs  = (const int*)d_in[2];
    const float* pa   = (const float*)d_in[3];
    const float* pb   = (const float*)d_in[4];
    const float* base = (const float*)d_in[5];
    float* out = (float*)d_out;

    int B = in_sizes[0] / (128 * 25);   // z is (B, 128, 25)
    lund_weight_kernel<<<B / 2, 256, 0, stream>>>(z, mT, obs, pa, pb, base, out);
}